// Round 2
// baseline (1006.052 us; speedup 1.0000x reference)
//
#include <hip/hip_runtime.h>
#include <hip/hip_bf16.h>
#include <cmath>

#define N_S   2048
#define C_CLS 100
#define K_CL  4
#define A_DIM 128
#define LDSROW 132   // padded row stride (floats); 132*4=528 bytes -> 16B aligned rows,
                     // bank = (4i + j) % 32 -> conflict-free column access

// ---------------------------------------------------------------------------
// Kernel 1: per (cl,k) block: Gauss-Jordan invert sigma[cl,k] in LDS (no pivoting,
// SPD well-conditioned), accumulate logdet, then for every sample n with
// labels[n]==cl compute score[n][k] = (x-mu)^T Sigma^{-1} (x-mu) + logdet.
// argmax_k log_p  ==  argmin_k score  (the d*log2pi term is k-constant).
// ---------------------------------------------------------------------------
__global__ __launch_bounds__(256) void k_invert_score(
    const float* __restrict__ sigma, const float* __restrict__ mu,
    const float* __restrict__ features, const int* __restrict__ labels,
    float* __restrict__ score)
{
    __shared__ __align__(16) float As[A_DIM * LDSROW];
    __shared__ __align__(16) float pr[A_DIM];
    __shared__ __align__(16) float fc[A_DIM];
    __shared__ int lab[N_S];

    const int tid = threadIdx.x;
    const int bid = blockIdx.x;          // cl*K + k  (k fastest, matches [C,K,A,A])
    const int cl  = bid >> 2;

    // stage labels (int32) once
    for (int t = tid; t < N_S; t += 256) lab[t] = labels[t];

    // stage sigma into padded LDS (coalesced 16B global reads)
    const float4* src = (const float4*)(sigma + (size_t)bid * A_DIM * A_DIM);
    for (int e4 = tid; e4 < A_DIM * 32; e4 += 256) {
        int i  = e4 >> 5;
        int j4 = (e4 & 31) << 2;
        *(float4*)&As[i * LDSROW + j4] = src[e4];
    }
    __syncthreads();

    // ---- in-place Gauss-Jordan inversion, logdet = sum log(pivots) ----
    float logdet = 0.0f;
    for (int p = 0; p < A_DIM; ++p) {
        float piv = As[p * LDSROW + p];      // LDS broadcast
        float ip  = 1.0f / piv;
        logdet += __logf(piv);               // uniform across threads
        if (tid < A_DIM) {
            pr[tid] = (tid == p) ? ip : As[p * LDSROW + tid] * ip;  // scaled pivot row
            fc[tid] = As[tid * LDSROW + p];                          // pivot column (old)
        }
        __syncthreads();
        const int pj4 = p >> 2, pcm = p & 3;
        #pragma unroll
        for (int s = 0; s < 16; ++s) {
            int e4  = tid + s * 256;        // thread owns fixed j4-group, rows i = tid>>5 + 8s
            int i   = e4 >> 5;
            int j4e = e4 & 31;
            float* ap = &As[i * LDSROW + (j4e << 2)];
            float4 a = *(float4*)ap;
            const float4 prv = *(const float4*)&pr[j4e << 2];
            if (i == p) {
                a = prv;                     // pr[p]==ip covers the (p,p) element
            } else {
                float fi = fc[i];
                a.x -= fi * prv.x; a.y -= fi * prv.y;
                a.z -= fi * prv.z; a.w -= fi * prv.w;
                if (j4e == pj4) ((float*)&a)[pcm] = -fi * ip;   // column p: assign, not subtract
            }
            *(float4*)ap = a;
        }
        __syncthreads();
    }
    // As = Sigma^{-1}; every thread holds logdet.

    // ---- per-sample quadratic form (one sample per wave) ----
    const int lane = tid & 63, w = tid >> 6;
    const float m0 = mu[(size_t)bid * A_DIM + lane];
    const float m1 = mu[(size_t)bid * A_DIM + 64 + lane];
    for (int n = w; n < N_S; n += 4) {
        if (lab[n] != cl) continue;          // wave-uniform branch
        float d0 = features[(size_t)n * A_DIM + lane]      - m0;
        float d1 = features[(size_t)n * A_DIM + 64 + lane] - m1;
        // p_j = sum_i ds_i * M[i][j]  for this lane's j in {lane, lane+64}
        float p0 = 0.f, p1 = 0.f;
        for (int i = 0; i < 64; ++i) {
            float b = __shfl(d0, i, 64);
            p0 += b * As[i * LDSROW + lane];
            p1 += b * As[i * LDSROW + 64 + lane];
        }
        for (int i = 0; i < 64; ++i) {
            float b = __shfl(d1, i, 64);
            p0 += b * As[(i + 64) * LDSROW + lane];
            p1 += b * As[(i + 64) * LDSROW + 64 + lane];
        }
        float q = d0 * p0 + d1 * p1;         // ds_j * p_j partials
        #pragma unroll
        for (int off = 32; off; off >>= 1) q += __shfl_xor(q, off, 64);
        if (lane == 0) score[n * K_CL + (bid & 3)] = q + logdet;
    }
}

// ---------------------------------------------------------------------------
// Kernel 2: per (cl,k) block: G = W * Sigma * W^T; store gdiag[c]=G[c,c] and
// gcol[c]=G[c,cl].  sigma2[n,c] = ratio*(gdiag[c] - 2*gcol[c] + gdiag[cl]).
// ---------------------------------------------------------------------------
__global__ __launch_bounds__(256) void k_gprep(
    const float* __restrict__ sigma, const float* __restrict__ weight,
    float* __restrict__ gdiag, float* __restrict__ gcol)
{
    __shared__ __align__(16) float Ss[A_DIM * LDSROW];
    const int tid = threadIdx.x, bid = blockIdx.x;
    const int cl  = bid >> 2;

    const float4* src = (const float4*)(sigma + (size_t)bid * A_DIM * A_DIM);
    for (int e4 = tid; e4 < A_DIM * 32; e4 += 256) {
        int i = e4 >> 5, j4 = (e4 & 31) << 2;
        *(float4*)&Ss[i * LDSROW + j4] = src[e4];
    }
    __syncthreads();

    const int lane = tid & 63, w = tid >> 6;
    const float wc0 = weight[cl * A_DIM + lane];
    const float wc1 = weight[cl * A_DIM + 64 + lane];
    for (int c = w; c < C_CLS; c += 4) {
        float r0 = weight[c * A_DIM + lane];
        float r1 = weight[c * A_DIM + 64 + lane];
        // h_j = sum_i W[c,i] * Sigma[i,j]   (lane's j in {lane, lane+64})
        float h0 = 0.f, h1 = 0.f;
        for (int i = 0; i < 64; ++i) {
            float b = __shfl(r0, i, 64);
            h0 += b * Ss[i * LDSROW + lane];
            h1 += b * Ss[i * LDSROW + 64 + lane];
        }
        for (int i = 0; i < 64; ++i) {
            float b = __shfl(r1, i, 64);
            h0 += b * Ss[(i + 64) * LDSROW + lane];
            h1 += b * Ss[(i + 64) * LDSROW + 64 + lane];
        }
        float pd = h0 * r0 + h1 * r1;   // -> G[c,c]
        float pc = h0 * wc0 + h1 * wc1; // -> G[c,cl]
        #pragma unroll
        for (int off = 32; off; off >>= 1) {
            pd += __shfl_xor(pd, off, 64);
            pc += __shfl_xor(pc, off, 64);
        }
        if (lane == 0) {
            gdiag[bid * C_CLS + c] = pd;
            gcol [bid * C_CLS + c] = pc;
        }
    }
}

// ---------------------------------------------------------------------------
// Kernel 3: y = X W^T + b   (one block per sample)
// ---------------------------------------------------------------------------
__global__ __launch_bounds__(128) void k_fc(
    const float* __restrict__ features, const float* __restrict__ weight,
    const float* __restrict__ bias, float* __restrict__ y)
{
    __shared__ __align__(16) float xs[A_DIM];
    const int n = blockIdx.x, t = threadIdx.x;
    xs[t] = features[(size_t)n * A_DIM + t];
    __syncthreads();
    if (t < C_CLS) {
        const float4* wr = (const float4*)(weight + t * A_DIM);
        const float4* xr = (const float4*)xs;
        float acc = bias[t];
        #pragma unroll
        for (int j = 0; j < 32; ++j) {
            float4 a = xr[j], b = wr[j];
            acc += a.x * b.x + a.y * b.y + a.z * b.z + a.w * b.w;
        }
        y[(size_t)n * C_CLS + t] = acc;
    }
}

// ---------------------------------------------------------------------------
// Kernel 4: per sample: kstar = argmin_k score, aug = y + 0.5*sigma2,
// log-softmax, loss += -logp[label]/N
// ---------------------------------------------------------------------------
__global__ __launch_bounds__(128) void k_final(
    const float* __restrict__ y, const int* __restrict__ labels,
    const float* __restrict__ score, const float* __restrict__ gdiag,
    const float* __restrict__ gcol, const float* __restrict__ ratio_p,
    float* __restrict__ loss)
{
    __shared__ float red[2], red2[2], acl_s;
    const int n = blockIdx.x, t = threadIdx.x;
    const int cl = labels[n];
    const float ratio = *ratio_p;

    float s0 = score[n * 4 + 0], s1 = score[n * 4 + 1];
    float s2 = score[n * 4 + 2], s3 = score[n * 4 + 3];
    int ks = 0; float bs = s0;                   // strict < : first-min == jnp first-max
    if (s1 < bs) { bs = s1; ks = 1; }
    if (s2 < bs) { bs = s2; ks = 2; }
    if (s3 < bs) { bs = s3; ks = 3; }

    const int base = (cl * 4 + ks) * C_CLS;
    const float gll = gdiag[base + cl];
    float aug = -INFINITY;
    if (t < C_CLS)
        aug = y[(size_t)n * C_CLS + t]
            + 0.5f * ratio * (gdiag[base + t] - 2.0f * gcol[base + t] + gll);

    float m = aug;
    #pragma unroll
    for (int off = 32; off; off >>= 1) m = fmaxf(m, __shfl_xor(m, off, 64));
    if ((t & 63) == 0) red[t >> 6] = m;
    __syncthreads();
    m = fmaxf(red[0], red[1]);

    float e = (t < C_CLS) ? expf(aug - m) : 0.0f;
    #pragma unroll
    for (int off = 32; off; off >>= 1) e += __shfl_xor(e, off, 64);
    if ((t & 63) == 0) red2[t >> 6] = e;
    if (t == cl) acl_s = aug;
    __syncthreads();

    if (t == 0) {
        float sum = red2[0] + red2[1];
        float lp = acl_s - m - logf(sum);
        atomicAdd(loss, -lp * (1.0f / (float)N_S));
    }
}

// ---------------------------------------------------------------------------
extern "C" void kernel_launch(void* const* d_in, const int* in_sizes, int n_in,
                              void* d_out, int out_size, void* d_ws, size_t ws_size,
                              hipStream_t stream) {
    const float* features = (const float*)d_in[0];
    const float* weight   = (const float*)d_in[1];
    const float* bias     = (const float*)d_in[2];
    // d_in[3] = pi : unused (q is one-hot for any pi > 0; argmax unaffected)
    const float* mu       = (const float*)d_in[4];
    const float* sigma    = (const float*)d_in[5];
    const int*   labels   = (const int*)d_in[6];   // harness delivers integers as int32
    const float* ratio    = (const float*)d_in[7];

    float* out   = (float*)d_out;   // [0] = loss, [1..204800] = y
    float* yout  = out + 1;
    float* score = (float*)d_ws;                  // N*K          = 8192 f32
    float* gdiag = score + N_S * K_CL;            // 400*100      = 40000 f32
    float* gcol  = gdiag + C_CLS * K_CL * C_CLS;  // 400*100      = 40000 f32

    hipMemsetAsync(d_out, 0, sizeof(float), stream);   // zero the loss accumulator

    k_invert_score<<<dim3(C_CLS * K_CL), dim3(256), 0, stream>>>(sigma, mu, features, labels, score);
    k_gprep      <<<dim3(C_CLS * K_CL), dim3(256), 0, stream>>>(sigma, weight, gdiag, gcol);
    k_fc         <<<dim3(N_S), dim3(128), 0, stream>>>(features, weight, bias, yout);
    k_final      <<<dim3(N_S), dim3(128), 0, stream>>>(yout, labels, score, gdiag, gcol, ratio, out);
}